// Round 1
// baseline (310.282 us; speedup 1.0000x reference)
//
#include <hip/hip_runtime.h>
#include <math.h>

#define Bb   2
#define Hh   56
#define Ww   56
#define Cc   256
#define NHh  8
#define HDd  32
#define KK   7
#define HWsz (Hh*Ww)
#define Mtot (Bb*Hh*Ww)   // 6272

// C[m,n] = sum_k A[m,k] * Wrow(n)[k]   (x @ W^T), optional per-channel scale + bias.
// Wrow(n) = W0[n] if n < n_split else W1[n - n_split].
// 64x64 tile, BK=16, 4x4 per thread, 256 threads.
__global__ __launch_bounds__(256) void gemm_xwT(
    const float* __restrict__ A, const float* __restrict__ W0,
    const float* __restrict__ W1, float* __restrict__ Cout,
    int Kdim, int N, int n_split, int scale_below, float scale,
    const float* __restrict__ bias)
{
    __shared__ float As[16][68];   // [k][m], pad 68 keeps float4 alignment, breaks pow2 stride
    __shared__ float Bs[16][68];   // [k][n]

    const int tid = threadIdx.x;
    const int tn  = tid & 15;      // 0..15 -> n sub-tile
    const int tm  = tid >> 4;      // 0..15 -> m sub-tile
    const int m0  = blockIdx.y * 64;
    const int n0  = blockIdx.x * 64;

    const int lrow = tid >> 2;         // 0..63
    const int lk4  = (tid & 3) * 4;    // 0,4,8,12

    const float* arow = A + (size_t)(m0 + lrow) * Kdim + lk4;
    const int n_idx = n0 + lrow;
    const float* brow = (n_idx < n_split ? W0 + (size_t)n_idx * Kdim
                                         : W1 + (size_t)(n_idx - n_split) * Kdim) + lk4;

    float acc[4][4] = {};

    for (int k0 = 0; k0 < Kdim; k0 += 16) {
        float4 a4 = *(const float4*)(arow + k0);
        float4 b4 = *(const float4*)(brow + k0);
        __syncthreads();
        As[lk4 + 0][lrow] = a4.x; As[lk4 + 1][lrow] = a4.y;
        As[lk4 + 2][lrow] = a4.z; As[lk4 + 3][lrow] = a4.w;
        Bs[lk4 + 0][lrow] = b4.x; Bs[lk4 + 1][lrow] = b4.y;
        Bs[lk4 + 2][lrow] = b4.z; Bs[lk4 + 3][lrow] = b4.w;
        __syncthreads();
        #pragma unroll
        for (int kk = 0; kk < 16; ++kk) {
            float4 av = *(const float4*)&As[kk][tm * 4];
            float4 bv = *(const float4*)&Bs[kk][tn * 4];
            acc[0][0] += av.x * bv.x; acc[0][1] += av.x * bv.y;
            acc[0][2] += av.x * bv.z; acc[0][3] += av.x * bv.w;
            acc[1][0] += av.y * bv.x; acc[1][1] += av.y * bv.y;
            acc[1][2] += av.y * bv.z; acc[1][3] += av.y * bv.w;
            acc[2][0] += av.z * bv.x; acc[2][1] += av.z * bv.y;
            acc[2][2] += av.z * bv.z; acc[2][3] += av.z * bv.w;
            acc[3][0] += av.w * bv.x; acc[3][1] += av.w * bv.y;
            acc[3][2] += av.w * bv.z; acc[3][3] += av.w * bv.w;
        }
    }

    #pragma unroll
    for (int i2 = 0; i2 < 4; ++i2) {
        const int m = m0 + tm * 4 + i2;
        float4 o;
        float v[4];
        #pragma unroll
        for (int j2 = 0; j2 < 4; ++j2) {
            const int ng = n0 + tn * 4 + j2;
            float val = acc[i2][j2];
            if (ng < scale_below) val *= scale;
            if (bias) val += bias[ng];
            v[j2] = val;
        }
        o.x = v[0]; o.y = v[1]; o.z = v[2]; o.w = v[3];
        *(float4*)(Cout + (size_t)m * N + n0 + tn * 4) = o;
    }
}

// One block per pixel. 256 threads = 256 channels (head = tid/32, d = tid%32).
// qkv layout per pixel m: [0..255]=q (already scaled), [256..511]=k, [512..767]=v.
__global__ __launch_bounds__(256) void nattn_kernel(
    const float* __restrict__ qkv, float* __restrict__ attn_out,
    float* __restrict__ attn_glob)
{
    const int m   = blockIdx.x;
    const int b   = m / HWsz;
    const int rem = m % HWsz;
    const int i   = rem / Ww;
    const int j   = rem % Ww;
    const int tid = threadIdx.x;
    const int head = tid >> 5;
    const int d    = tid & 31;

    int ih0 = i - 3; if (ih0 < 0) ih0 = 0; if (ih0 > Hh - KK) ih0 = Hh - KK;
    int iw0 = j - 3; if (iw0 < 0) iw0 = 0; if (iw0 > Ww - KK) iw0 = Ww - KK;

    __shared__ float s[NHh][KK * KK];

    const float qv = qkv[(size_t)m * 768 + tid];
    const int base_b = b * HWsz;

    for (int p = 0; p < KK * KK; ++p) {
        const int ii = ih0 + p / KK;
        const int jj = iw0 + p % KK;
        const int mp = base_b + ii * Ww + jj;
        const float kvv = qkv[(size_t)mp * 768 + 256 + tid];
        float part = qv * kvv;
        part += __shfl_xor(part, 16);
        part += __shfl_xor(part, 8);
        part += __shfl_xor(part, 4);
        part += __shfl_xor(part, 2);
        part += __shfl_xor(part, 1);
        if (d == 0) s[head][p] = part;
    }
    __syncthreads();

    if (tid < NHh) {
        float mx = -1e30f;
        for (int p = 0; p < KK * KK; ++p) mx = fmaxf(mx, s[tid][p]);
        float sum = 0.f;
        for (int p = 0; p < KK * KK; ++p) {
            float e = __expf(s[tid][p] - mx);
            s[tid][p] = e;
            sum += e;
        }
        const float inv = 1.f / sum;
        for (int p = 0; p < KK * KK; ++p) s[tid][p] *= inv;
    }
    __syncthreads();

    // attn output: (B, NH, H, W, 49)
    for (int idx = tid; idx < NHh * KK * KK; idx += 256) {
        const int h2 = idx / (KK * KK);
        const int p2 = idx - h2 * (KK * KK);
        attn_glob[((size_t)(b * NHh + h2) * HWsz + rem) * (KK * KK) + p2] = s[h2][p2];
    }

    // PV: per-channel accumulate
    float acc = 0.f;
    for (int p = 0; p < KK * KK; ++p) {
        const int ii = ih0 + p / KK;
        const int jj = iw0 + p % KK;
        const int mp = base_b + ii * Ww + jj;
        acc += s[head][p] * qkv[(size_t)mp * 768 + 512 + tid];
    }
    attn_out[(size_t)m * 256 + tid] = acc;
}

extern "C" void kernel_launch(void* const* d_in, const int* in_sizes, int n_in,
                              void* d_out, int out_size, void* d_ws, size_t ws_size,
                              hipStream_t stream)
{
    const float* x      = (const float*)d_in[0];
    const float* w_qk   = (const float*)d_in[1];
    const float* w_v    = (const float*)d_in[2];
    const float* w_proj = (const float*)d_in[3];
    const float* b_proj = (const float*)d_in[4];

    float* out       = (float*)d_out;                    // chunk 0: (B,H,W,C)
    float* attn_glob = out + (size_t)Mtot * Cc;          // chunk 1: (B,NH,H,W,49)

    float* qkv_ws  = (float*)d_ws;                       // M x 768 (q|k|v)
    float* attn_ws = qkv_ws + (size_t)Mtot * 768;        // M x 256

    const float scale = 0.17677669529663687f;            // HD^-0.5

    // QKV projection: N = 768 (512 from w_qk, 256 from w_v); scale q channels (<256)
    gemm_xwT<<<dim3(768 / 64, Mtot / 64), 256, 0, stream>>>(
        x, w_qk, w_v, qkv_ws, Cc, 768, 512, 256, scale, nullptr);

    // Neighborhood attention
    nattn_kernel<<<Mtot, 256, 0, stream>>>(qkv_ws, attn_ws, attn_glob);

    // Output projection + bias
    gemm_xwT<<<dim3(256 / 64, Mtot / 64), 256, 0, stream>>>(
        attn_ws, w_proj, w_proj, out, Cc, Cc, 1 << 30, 0, 1.f, b_proj);
}

// Round 2
// 153.165 us; speedup vs baseline: 2.0258x; 2.0258x over previous
//
#include <hip/hip_runtime.h>
#include <math.h>

#define Bb   2
#define Hh   56
#define Ww   56
#define Cc   256
#define NHh  8
#define HDd  32
#define KK   7
#define HWsz (Hh*Ww)
#define Mtot (Bb*Hh*Ww)   // 6272

// C[m,n] = sum_k A[m,k] * Wrow(n)[k]   (x @ W^T), optional per-channel scale + bias.
// Wrow(n) = W0[n] if n < n_split else W1[n - n_split].
// 64x64 tile, BK=16, 4x4 per thread, 256 threads.
__global__ __launch_bounds__(256) void gemm_xwT(
    const float* __restrict__ A, const float* __restrict__ W0,
    const float* __restrict__ W1, float* __restrict__ Cout,
    int Kdim, int N, int n_split, int scale_below, float scale,
    const float* __restrict__ bias)
{
    __shared__ float As[16][68];
    __shared__ float Bs[16][68];

    const int tid = threadIdx.x;
    const int tn  = tid & 15;
    const int tm  = tid >> 4;
    const int m0  = blockIdx.y * 64;
    const int n0  = blockIdx.x * 64;

    const int lrow = tid >> 2;
    const int lk4  = (tid & 3) * 4;

    const float* arow = A + (size_t)(m0 + lrow) * Kdim + lk4;
    const int n_idx = n0 + lrow;
    const float* brow = (n_idx < n_split ? W0 + (size_t)n_idx * Kdim
                                         : W1 + (size_t)(n_idx - n_split) * Kdim) + lk4;

    float acc[4][4] = {};

    for (int k0 = 0; k0 < Kdim; k0 += 16) {
        float4 a4 = *(const float4*)(arow + k0);
        float4 b4 = *(const float4*)(brow + k0);
        __syncthreads();
        As[lk4 + 0][lrow] = a4.x; As[lk4 + 1][lrow] = a4.y;
        As[lk4 + 2][lrow] = a4.z; As[lk4 + 3][lrow] = a4.w;
        Bs[lk4 + 0][lrow] = b4.x; Bs[lk4 + 1][lrow] = b4.y;
        Bs[lk4 + 2][lrow] = b4.z; Bs[lk4 + 3][lrow] = b4.w;
        __syncthreads();
        #pragma unroll
        for (int kk = 0; kk < 16; ++kk) {
            float4 av = *(const float4*)&As[kk][tm * 4];
            float4 bv = *(const float4*)&Bs[kk][tn * 4];
            acc[0][0] += av.x * bv.x; acc[0][1] += av.x * bv.y;
            acc[0][2] += av.x * bv.z; acc[0][3] += av.x * bv.w;
            acc[1][0] += av.y * bv.x; acc[1][1] += av.y * bv.y;
            acc[1][2] += av.y * bv.z; acc[1][3] += av.y * bv.w;
            acc[2][0] += av.z * bv.x; acc[2][1] += av.z * bv.y;
            acc[2][2] += av.z * bv.z; acc[2][3] += av.z * bv.w;
            acc[3][0] += av.w * bv.x; acc[3][1] += av.w * bv.y;
            acc[3][2] += av.w * bv.z; acc[3][3] += av.w * bv.w;
        }
    }

    #pragma unroll
    for (int i2 = 0; i2 < 4; ++i2) {
        const int m = m0 + tm * 4 + i2;
        float v[4];
        #pragma unroll
        for (int j2 = 0; j2 < 4; ++j2) {
            const int ng = n0 + tn * 4 + j2;
            float val = acc[i2][j2];
            if (ng < scale_below) val *= scale;
            if (bias) val += bias[ng];
            v[j2] = val;
        }
        float4 o; o.x = v[0]; o.y = v[1]; o.z = v[2]; o.w = v[3];
        *(float4*)(Cout + (size_t)m * N + n0 + tn * 4) = o;
    }
}

// Tiled neighborhood attention: one block = 8x8 query tile for one (b, head).
// K (then V) for the 14x14 neighborhood staged in LDS; Q in registers.
// Thread layout: tid = 4*q + r; q = query in tile (0..63), r = key-phase (0..3).
__global__ __launch_bounds__(256) void nattn_tiled(
    const float* __restrict__ qkv, float* __restrict__ attn_out,
    float* __restrict__ attn_glob)
{
    __shared__ float Ks[196 * 36];   // K then V, stride 36 (pad: 36%32=4)
    __shared__ float Ss[64 * 50];    // Q staging (stride 36), then probs (stride 50)

    const int bx   = blockIdx.x;
    const int head = bx & 7;
    int tq = bx >> 3;
    const int tj = tq % 7; tq /= 7;
    const int ti = tq % 7;
    const int b  = tq / 7;

    const int tid = threadIdx.x;

    int base_h = ti * 8 - 3; if (base_h < 0) base_h = 0; if (base_h > Hh - 14) base_h = Hh - 14;
    int base_w = tj * 8 - 3; if (base_w < 0) base_w = 0; if (base_w > Ww - 14) base_w = Ww - 14;

    const int pixb = b * HWsz;
    const int hoff = head * 32;

    // stage K (196 x 32) and Q (64 x 32)
    for (int idx = tid; idx < 196 * 8; idx += 256) {
        const int p = idx >> 3, c = idx & 7;
        const int pix = pixb + (base_h + p / 14) * Ww + base_w + p % 14;
        *(float4*)&Ks[p * 36 + c * 4] =
            *(const float4*)&qkv[(size_t)pix * 768 + 256 + hoff + c * 4];
    }
    for (int idx = tid; idx < 64 * 8; idx += 256) {
        const int qq = idx >> 3, c = idx & 7;
        const int pix = pixb + (ti * 8 + (qq >> 3)) * Ww + tj * 8 + (qq & 7);
        *(float4*)&Ss[qq * 36 + c * 4] =
            *(const float4*)&qkv[(size_t)pix * 768 + hoff + c * 4];
    }
    __syncthreads();

    const int q  = tid >> 2;
    const int r  = tid & 3;
    const int qi = ti * 8 + (q >> 3);
    const int qj = tj * 8 + (q & 7);
    int ih0 = qi - 3; if (ih0 < 0) ih0 = 0; if (ih0 > Hh - 7) ih0 = Hh - 7;
    int iw0 = qj - 3; if (iw0 < 0) iw0 = 0; if (iw0 > Ww - 7) iw0 = Ww - 7;
    const int lh0 = ih0 - base_h, lw0 = iw0 - base_w;

    float4 qreg[8];
    #pragma unroll
    for (int c = 0; c < 8; ++c) qreg[c] = *(const float4*)&Ss[q * 36 + c * 4];
    __syncthreads();   // Q regs loaded; Ss free for probs

    // QK: lane r handles keys k = r, r+4, ... (13 or 12 keys)
    float sc[13];
    float mx = -1e30f;
    #pragma unroll
    for (int tt = 0; tt < 13; ++tt) {
        const int k = r + 4 * tt;
        if (k < 49) {
            const int krow = (lh0 + k / 7) * 14 + lw0 + k % 7;
            const float* kp = &Ks[krow * 36];
            float acc = 0.f;
            #pragma unroll
            for (int c = 0; c < 8; ++c) {
                const float4 kv = *(const float4*)(kp + c * 4);
                acc += qreg[c].x * kv.x + qreg[c].y * kv.y
                     + qreg[c].z * kv.z + qreg[c].w * kv.w;
            }
            sc[tt] = acc;
            mx = fmaxf(mx, acc);
        }
    }
    mx = fmaxf(mx, __shfl_xor(mx, 1));
    mx = fmaxf(mx, __shfl_xor(mx, 2));
    float sum = 0.f;
    #pragma unroll
    for (int tt = 0; tt < 13; ++tt) {
        const int k = r + 4 * tt;
        if (k < 49) { sc[tt] = __expf(sc[tt] - mx); sum += sc[tt]; }
    }
    sum += __shfl_xor(sum, 1);
    sum += __shfl_xor(sum, 2);
    const float inv = 1.f / sum;
    #pragma unroll
    for (int tt = 0; tt < 13; ++tt) {
        const int k = r + 4 * tt;
        if (k < 49) Ss[q * 50 + k] = sc[tt] * inv;
    }
    __syncthreads();   // all K reads + prob writes done

    // V overwrites K buffer; attn written to global from Ss (independent)
    for (int idx = tid; idx < 196 * 8; idx += 256) {
        const int p = idx >> 3, c = idx & 7;
        const int pix = pixb + (base_h + p / 14) * Ww + base_w + p % 14;
        *(float4*)&Ks[p * 36 + c * 4] =
            *(const float4*)&qkv[(size_t)pix * 768 + 512 + hoff + c * 4];
    }
    const size_t agbase = (size_t)(b * NHh + head) * HWsz;
    for (int idx = tid; idx < 64 * 49; idx += 256) {
        const int qq = idx / 49, k = idx - qq * 49;
        attn_glob[(agbase + (ti * 8 + (qq >> 3)) * Ww + tj * 8 + (qq & 7)) * 49 + k]
            = Ss[qq * 50 + k];
    }
    __syncthreads();

    // PV: thread (q, r) owns dims d = 8r .. 8r+7
    const int d0 = r * 8;
    float4 a0 = {0, 0, 0, 0}, a1 = {0, 0, 0, 0};
    #pragma unroll
    for (int k = 0; k < 49; ++k) {
        const float pr = Ss[q * 50 + k];
        const int vrow = (lh0 + k / 7) * 14 + lw0 + k % 7;
        const float4 v0 = *(const float4*)&Ks[vrow * 36 + d0];
        const float4 v1 = *(const float4*)&Ks[vrow * 36 + d0 + 4];
        a0.x += pr * v0.x; a0.y += pr * v0.y; a0.z += pr * v0.z; a0.w += pr * v0.w;
        a1.x += pr * v1.x; a1.y += pr * v1.y; a1.z += pr * v1.z; a1.w += pr * v1.w;
    }
    float* op = attn_out + (size_t)(pixb + qi * Ww + qj) * 256 + hoff + d0;
    *(float4*)op = a0;
    *(float4*)(op + 4) = a1;
}

extern "C" void kernel_launch(void* const* d_in, const int* in_sizes, int n_in,
                              void* d_out, int out_size, void* d_ws, size_t ws_size,
                              hipStream_t stream)
{
    const float* x      = (const float*)d_in[0];
    const float* w_qk   = (const float*)d_in[1];
    const float* w_v    = (const float*)d_in[2];
    const float* w_proj = (const float*)d_in[3];
    const float* b_proj = (const float*)d_in[4];

    float* out       = (float*)d_out;                    // chunk 0: (B,H,W,C)
    float* attn_glob = out + (size_t)Mtot * Cc;          // chunk 1: (B,NH,H,W,49)

    float* qkv_ws  = (float*)d_ws;                       // M x 768 (q|k|v)
    float* attn_ws = qkv_ws + (size_t)Mtot * 768;        // M x 256

    const float scale = 0.17677669529663687f;            // HD^-0.5

    gemm_xwT<<<dim3(768 / 64, Mtot / 64), 256, 0, stream>>>(
        x, w_qk, w_v, qkv_ws, Cc, 768, 512, 256, scale, nullptr);

    nattn_tiled<<<Bb * 7 * 7 * NHh, 256, 0, stream>>>(qkv_ws, attn_ws, attn_glob);

    gemm_xwT<<<dim3(256 / 64, Mtot / 64), 256, 0, stream>>>(
        attn_ws, w_proj, w_proj, out, Cc, Cc, 1 << 30, 0, 1.f, b_proj);
}

// Round 3
// 115.824 us; speedup vs baseline: 2.6789x; 1.3224x over previous
//
#include <hip/hip_runtime.h>
#include <math.h>

#define Bb   2
#define Hh   56
#define Ww   56
#define Cc   256
#define NHh  8
#define HDd  32
#define KK   7
#define HWsz (Hh*Ww)
#define Mtot (Bb*Hh*Ww)   // 6272

typedef __bf16 bf16x8 __attribute__((ext_vector_type(8)));
typedef float  f32x4  __attribute__((ext_vector_type(4)));

// C[m,n] = sum_k A[m,k] * Wrow(n)[k]  (x @ W^T) via bf16 MFMA, fp32 accum.
// Wrow(n) = W0[n] if n < n_split else W1[n - n_split].
// 64x64 tile, BK=64, 256 threads (4 waves); wave w owns rows [w*16, w*16+16).
// LDS layout: frag-ordered 512-elem blocks blk = ks*4 + sub; within a block,
// elem (row, k32) at row*32 + chunkswz(k32>>3, row)*8 + (k32&7).
__global__ __launch_bounds__(256) void gemm_bf16(
    const float* __restrict__ A, const float* __restrict__ W0,
    const float* __restrict__ W1, float* __restrict__ Cout,
    int Kdim, int N, int n_split, int scale_below, float scale,
    const float* __restrict__ bias)
{
    __shared__ __bf16 As[4096];
    __shared__ __bf16 Bs[4096];

    const int tid = threadIdx.x;
    const int m0  = blockIdx.y * 64;
    const int n0  = blockIdx.x * 64;

    // staging: thread t covers row mm = t>>2, k-chunk range q = t&3 (16 k each)
    const int mm = tid >> 2;
    const int q  = tid & 3;
    const float* arow = A + (size_t)(m0 + mm) * Kdim + q * 16;
    const int n_idx = n0 + mm;
    const float* brow = (n_idx < n_split ? W0 + (size_t)n_idx * Kdim
                                         : W1 + (size_t)(n_idx - n_split) * Kdim) + q * 16;

    const int ks_st  = q >> 1;          // which 32-k half this thread stages
    const int sub_st = mm >> 4;         // 16-row sub-block
    const int row_st = mm & 15;
    const int c0_st  = (q & 1) * 2;     // logical 16B-chunk within the 32-k half
    const int blk_st = ks_st * 4 + sub_st;
    const int off0 = blk_st * 512 + row_st * 32 + ((c0_st ^ (row_st & 3)) * 8);
    const int off1 = blk_st * 512 + row_st * 32 + (((c0_st + 1) ^ (row_st & 3)) * 8);

    // compute: wave w = m-subtile; lane -> (row = lane&15, chunk c = lane>>4)
    const int w    = tid >> 6;
    const int lane = tid & 63;
    const int fr_row = lane & 15;
    const int fr_c   = lane >> 4;
    const int fr_off = fr_row * 32 + ((fr_c ^ (fr_row & 3)) * 8);

    f32x4 acc[4] = {};

    for (int k0 = 0; k0 < Kdim; k0 += 64) {
        float4 a0 = *(const float4*)(arow + k0);
        float4 a1 = *(const float4*)(arow + k0 + 4);
        float4 a2 = *(const float4*)(arow + k0 + 8);
        float4 a3 = *(const float4*)(arow + k0 + 12);
        float4 b0 = *(const float4*)(brow + k0);
        float4 b1 = *(const float4*)(brow + k0 + 4);
        float4 b2 = *(const float4*)(brow + k0 + 8);
        float4 b3 = *(const float4*)(brow + k0 + 12);
        __syncthreads();   // previous iter's frag reads done before overwrite
        bf16x8 av0 = { (__bf16)a0.x, (__bf16)a0.y, (__bf16)a0.z, (__bf16)a0.w,
                       (__bf16)a1.x, (__bf16)a1.y, (__bf16)a1.z, (__bf16)a1.w };
        bf16x8 av1 = { (__bf16)a2.x, (__bf16)a2.y, (__bf16)a2.z, (__bf16)a2.w,
                       (__bf16)a3.x, (__bf16)a3.y, (__bf16)a3.z, (__bf16)a3.w };
        bf16x8 bv0 = { (__bf16)b0.x, (__bf16)b0.y, (__bf16)b0.z, (__bf16)b0.w,
                       (__bf16)b1.x, (__bf16)b1.y, (__bf16)b1.z, (__bf16)b1.w };
        bf16x8 bv1 = { (__bf16)b2.x, (__bf16)b2.y, (__bf16)b2.z, (__bf16)b2.w,
                       (__bf16)b3.x, (__bf16)b3.y, (__bf16)b3.z, (__bf16)b3.w };
        *(bf16x8*)&As[off0] = av0;
        *(bf16x8*)&As[off1] = av1;
        *(bf16x8*)&Bs[off0] = bv0;
        *(bf16x8*)&Bs[off1] = bv1;
        __syncthreads();
        #pragma unroll
        for (int ks = 0; ks < 2; ++ks) {
            bf16x8 af = *(const bf16x8*)&As[(ks * 4 + w) * 512 + fr_off];
            #pragma unroll
            for (int n = 0; n < 4; ++n) {
                bf16x8 bfr = *(const bf16x8*)&Bs[(ks * 4 + n) * 512 + fr_off];
                acc[n] = __builtin_amdgcn_mfma_f32_16x16x32_bf16(af, bfr, acc[n], 0, 0, 0);
            }
        }
    }

    // epilogue: C/D mapping col = lane&15, row = (lane>>4)*4 + reg
    #pragma unroll
    for (int n = 0; n < 4; ++n) {
        const int gcol = n0 + n * 16 + fr_row;   // fr_row == lane&15 == col
        const float sc_ = (gcol < scale_below) ? scale : 1.f;
        const float bs_ = bias ? bias[gcol] : 0.f;
        #pragma unroll
        for (int r = 0; r < 4; ++r) {
            const int grow = m0 + w * 16 + fr_c * 4 + r;
            Cout[(size_t)grow * N + gcol] = acc[n][r] * sc_ + bs_;
        }
    }
}

// Tiled neighborhood attention: one block = 8x8 query tile for one (b, head).
__global__ __launch_bounds__(256) void nattn_tiled(
    const float* __restrict__ qkv, float* __restrict__ attn_out,
    float* __restrict__ attn_glob)
{
    __shared__ float Ks[196 * 36];
    __shared__ float Ss[64 * 50];

    const int bx   = blockIdx.x;
    const int head = bx & 7;
    int tq = bx >> 3;
    const int tj = tq % 7; tq /= 7;
    const int ti = tq % 7;
    const int b  = tq / 7;

    const int tid = threadIdx.x;

    int base_h = ti * 8 - 3; if (base_h < 0) base_h = 0; if (base_h > Hh - 14) base_h = Hh - 14;
    int base_w = tj * 8 - 3; if (base_w < 0) base_w = 0; if (base_w > Ww - 14) base_w = Ww - 14;

    const int pixb = b * HWsz;
    const int hoff = head * 32;

    for (int idx = tid; idx < 196 * 8; idx += 256) {
        const int p = idx >> 3, c = idx & 7;
        const int pix = pixb + (base_h + p / 14) * Ww + base_w + p % 14;
        *(float4*)&Ks[p * 36 + c * 4] =
            *(const float4*)&qkv[(size_t)pix * 768 + 256 + hoff + c * 4];
    }
    for (int idx = tid; idx < 64 * 8; idx += 256) {
        const int qq = idx >> 3, c = idx & 7;
        const int pix = pixb + (ti * 8 + (qq >> 3)) * Ww + tj * 8 + (qq & 7);
        *(float4*)&Ss[qq * 36 + c * 4] =
            *(const float4*)&qkv[(size_t)pix * 768 + hoff + c * 4];
    }
    __syncthreads();

    const int q  = tid >> 2;
    const int r  = tid & 3;
    const int qi = ti * 8 + (q >> 3);
    const int qj = tj * 8 + (q & 7);
    int ih0 = qi - 3; if (ih0 < 0) ih0 = 0; if (ih0 > Hh - 7) ih0 = Hh - 7;
    int iw0 = qj - 3; if (iw0 < 0) iw0 = 0; if (iw0 > Ww - 7) iw0 = Ww - 7;
    const int lh0 = ih0 - base_h, lw0 = iw0 - base_w;

    float4 qreg[8];
    #pragma unroll
    for (int c = 0; c < 8; ++c) qreg[c] = *(const float4*)&Ss[q * 36 + c * 4];
    __syncthreads();

    float sc[13];
    float mx = -1e30f;
    #pragma unroll
    for (int tt = 0; tt < 13; ++tt) {
        const int k = r + 4 * tt;
        if (k < 49) {
            const int krow = (lh0 + k / 7) * 14 + lw0 + k % 7;
            const float* kp = &Ks[krow * 36];
            float acc = 0.f;
            #pragma unroll
            for (int c = 0; c < 8; ++c) {
                const float4 kv = *(const float4*)(kp + c * 4);
                acc += qreg[c].x * kv.x + qreg[c].y * kv.y
                     + qreg[c].z * kv.z + qreg[c].w * kv.w;
            }
            sc[tt] = acc;
            mx = fmaxf(mx, acc);
        }
    }
    mx = fmaxf(mx, __shfl_xor(mx, 1));
    mx = fmaxf(mx, __shfl_xor(mx, 2));
    float sum = 0.f;
    #pragma unroll
    for (int tt = 0; tt < 13; ++tt) {
        const int k = r + 4 * tt;
        if (k < 49) { sc[tt] = __expf(sc[tt] - mx); sum += sc[tt]; }
    }
    sum += __shfl_xor(sum, 1);
    sum += __shfl_xor(sum, 2);
    const float inv = 1.f / sum;
    #pragma unroll
    for (int tt = 0; tt < 13; ++tt) {
        const int k = r + 4 * tt;
        if (k < 49) Ss[q * 50 + k] = sc[tt] * inv;
    }
    __syncthreads();

    for (int idx = tid; idx < 196 * 8; idx += 256) {
        const int p = idx >> 3, c = idx & 7;
        const int pix = pixb + (base_h + p / 14) * Ww + base_w + p % 14;
        *(float4*)&Ks[p * 36 + c * 4] =
            *(const float4*)&qkv[(size_t)pix * 768 + 512 + hoff + c * 4];
    }
    const size_t agbase = (size_t)(b * NHh + head) * HWsz;
    for (int idx = tid; idx < 64 * 49; idx += 256) {
        const int qq = idx / 49, k = idx - qq * 49;
        attn_glob[(agbase + (ti * 8 + (qq >> 3)) * Ww + tj * 8 + (qq & 7)) * 49 + k]
            = Ss[qq * 50 + k];
    }
    __syncthreads();

    const int d0 = r * 8;
    float4 a0 = {0, 0, 0, 0}, a1 = {0, 0, 0, 0};
    #pragma unroll
    for (int k = 0; k < 49; ++k) {
        const float pr = Ss[q * 50 + k];
        const int vrow = (lh0 + k / 7) * 14 + lw0 + k % 7;
        const float4 v0 = *(const float4*)&Ks[vrow * 36 + d0];
        const float4 v1 = *(const float4*)&Ks[vrow * 36 + d0 + 4];
        a0.x += pr * v0.x; a0.y += pr * v0.y; a0.z += pr * v0.z; a0.w += pr * v0.w;
        a1.x += pr * v1.x; a1.y += pr * v1.y; a1.z += pr * v1.z; a1.w += pr * v1.w;
    }
    float* op = attn_out + (size_t)(pixb + qi * Ww + qj) * 256 + hoff + d0;
    *(float4*)op = a0;
    *(float4*)(op + 4) = a1;
}

extern "C" void kernel_launch(void* const* d_in, const int* in_sizes, int n_in,
                              void* d_out, int out_size, void* d_ws, size_t ws_size,
                              hipStream_t stream)
{
    const float* x      = (const float*)d_in[0];
    const float* w_qk   = (const float*)d_in[1];
    const float* w_v    = (const float*)d_in[2];
    const float* w_proj = (const float*)d_in[3];
    const float* b_proj = (const float*)d_in[4];

    float* out       = (float*)d_out;                    // chunk 0: (B,H,W,C)
    float* attn_glob = out + (size_t)Mtot * Cc;          // chunk 1: (B,NH,H,W,49)

    float* qkv_ws  = (float*)d_ws;                       // M x 768 (q|k|v)
    float* attn_ws = qkv_ws + (size_t)Mtot * 768;        // M x 256

    const float scale = 0.17677669529663687f;            // HD^-0.5

    gemm_bf16<<<dim3(768 / 64, Mtot / 64), 256, 0, stream>>>(
        x, w_qk, w_v, qkv_ws, Cc, 768, 512, 256, scale, nullptr);

    nattn_tiled<<<Bb * 7 * 7 * NHh, 256, 0, stream>>>(qkv_ws, attn_ws, attn_glob);

    gemm_bf16<<<dim3(256 / 64, Mtot / 64), 256, 0, stream>>>(
        attn_ws, w_proj, w_proj, out, Cc, Cc, 1 << 30, 0, 1.f, b_proj);
}